// Round 4
// baseline (225.005 us; speedup 1.0000x reference)
//
#include <hip/hip_runtime.h>
#include <hip/hip_bf16.h>

// SkeletonLoss: out = sum_b mean_e ( ||p[b,s0]-p[b,s1]|| - init_len[e] )^2
// B=64, N=100000, E=200000.
//
// R4: row-sweep tile-pair processing with register double-buffering.
// Points split into T=10 tiles of 10000 (80 KB fp32). Edges bucketed by
// canonical tile pair (prepass: hist/scan/scatter). Main kernel: 256 blocks
// (1/CU, 160 KB LDS = tileA + tileB). Work item = (batch,row a): pin tile a
// in tileA, sweep b=a..9 through tileB. Tile b+2 is prefetched into 5xfloat4
// registers while bucket (a,b) computes -> load latency hidden, and loads
// drop from 100 to 55 per batch (512->282 MB streamed). XCD-affine: block%8
// = slot owns batches [slot*8,slot*8+8). Per-slot dynamic row queue (atomic)
// for load balance, heavy rows (a=0) first.

#define T_TILES 10
#define PTILE   10000
#define NB2     (T_TILES * T_TILES)   // 100 buckets (upper-tri live)
#define MAIN_BLOCK 1024
#define TILE_F4 (PTILE * 2 / 4)       // 5000 float4 per tile
#define CHUNKS  5                      // ceil(5000/1024)

// ---- ws layout (bytes) ----
// [0,    1024)  cnt[256]
// [1024, 2052)  off[257]
// [2176, 3200)  cur[256]
// [3200, 3232)  rowctr[8]
// [4096, 4096+8E) recs int2[E]  {packed oA|oB<<14, bitcast(len)}
#define WS_CNT  0
#define WS_OFF  1024
#define WS_CUR  2176
#define WS_CTR  3200
#define WS_REC  4096

__device__ __forceinline__ void edge_bucket(int i0, int i1, int& bkt, unsigned& pk) {
    int ta = i0 / PTILE, tb = i1 / PTILE;
    int oa = i0 - ta * PTILE, ob = i1 - tb * PTILE;
    int a, b, oA, oB;
    if (ta <= tb) { a = ta; b = tb; oA = oa; oB = ob; }
    else          { a = tb; b = ta; oA = ob; oB = oa; }
    bkt = a * T_TILES + b;
    pk = (unsigned)oA | ((unsigned)oB << 14);
}

__global__ __launch_bounds__(1024) void hist_kernel(
    const int2* __restrict__ skel, int* __restrict__ cnt, int E)
{
    __shared__ int h[256];
    if (threadIdx.x < 256) h[threadIdx.x] = 0;
    __syncthreads();
    int e = blockIdx.x * blockDim.x + threadIdx.x;
    if (e < E) {
        int2 s = skel[e];
        int bkt; unsigned pk;
        edge_bucket(s.x, s.y, bkt, pk);
        atomicAdd(&h[bkt], 1);
    }
    __syncthreads();
    if (threadIdx.x < 256 && h[threadIdx.x])
        atomicAdd(&cnt[threadIdx.x], h[threadIdx.x]);
}

__global__ __launch_bounds__(256) void scan_kernel(
    const int* __restrict__ cnt, int* __restrict__ off, int* __restrict__ cur)
{
    __shared__ int s[256];
    int t = threadIdx.x;
    int v = cnt[t];   // bins >= NB2 are zero (memset)
    s[t] = v;
    __syncthreads();
    #pragma unroll
    for (int d = 1; d < 256; d <<= 1) {
        int x = (t >= d) ? s[t - d] : 0;
        __syncthreads();
        s[t] += x;
        __syncthreads();
    }
    int ex = s[t] - v;                 // exclusive prefix
    if (t <= NB2) off[t] = ex;         // off[NB2] = E
    if (t < NB2)  cur[t] = ex;
}

__global__ __launch_bounds__(1024) void scatter_kernel(
    const int2* __restrict__ skel, const float* __restrict__ init_len,
    int* __restrict__ cur, int2* __restrict__ recs, int E)
{
    __shared__ int h[256];
    __shared__ int base[256];
    if (threadIdx.x < 256) h[threadIdx.x] = 0;
    __syncthreads();
    int e = blockIdx.x * blockDim.x + threadIdx.x;
    int bkt = 0, lrank = 0; unsigned pk = 0;
    if (e < E) {
        int2 s = skel[e];
        edge_bucket(s.x, s.y, bkt, pk);
        lrank = atomicAdd(&h[bkt], 1);
    }
    __syncthreads();
    if (threadIdx.x < 256 && h[threadIdx.x])
        base[threadIdx.x] = atomicAdd(&cur[threadIdx.x], h[threadIdx.x]);
    __syncthreads();
    if (e < E) {
        int pos = base[bkt] + lrank;
        recs[pos] = make_int2((int)pk, __float_as_int(init_len[e]));
    }
}

__global__ __launch_bounds__(MAIN_BLOCK) void skeleton_main_kernel(
    const float2* __restrict__ pts, const int2* __restrict__ recs,
    const int* __restrict__ off, int* __restrict__ rowctr,
    float* __restrict__ out, int N, float inv_E)
{
    __shared__ float2 tileA[PTILE];   // 80,000 B
    __shared__ float2 tileB[PTILE];   // 80,000 B
    __shared__ float wsum[MAIN_BLOCK / 64];
    __shared__ int sh_w;

    const int slot = blockIdx.x & 7;   // XCD affinity
    const int tid = threadIdx.x;
    float acc = 0.0f;

    if (tid == 0) sh_w = atomicAdd(&rowctr[slot], 1);
    __syncthreads();
    int w = sh_w;

    while (w < 8 * T_TILES) {
        const int a = w >> 3;                       // row (heavy rows first)
        const int batch = slot * 8 + (w & 7);
        const float2* pb = pts + (size_t)batch * N;

        // stage tile a -> regs (issue loads now, commit after barrier)
        float4 rA[CHUNKS];
        {
            const float4* g = (const float4*)(pb + a * PTILE);
            #pragma unroll
            for (int k = 0; k < CHUNKS; ++k) {
                int idx = tid + k * MAIN_BLOCK;
                if (idx < TILE_F4) rA[k] = g[idx];
            }
        }
        __syncthreads();               // prev row's tileA readers done
        {
            float4* d = (float4*)tileA;
            #pragma unroll
            for (int k = 0; k < CHUNKS; ++k) {
                int idx = tid + k * MAIN_BLOCK;
                if (idx < TILE_F4) d[idx] = rA[k];
            }
        }
        // stage tile a+1 -> regs (lands during first bucket's compute)
        float4 rB[CHUNKS];
        if (a + 1 < T_TILES) {
            const float4* g = (const float4*)(pb + (a + 1) * PTILE);
            #pragma unroll
            for (int k = 0; k < CHUNKS; ++k) {
                int idx = tid + k * MAIN_BLOCK;
                if (idx < TILE_F4) rB[k] = g[idx];
            }
        }
        __syncthreads();               // tileA visible

        for (int b = a; b < T_TILES; ++b) {
            const float2* t1 = (b == a) ? tileA : tileB;
            const int p = a * T_TILES + b;
            const int lo = off[p], hi = off[p + 1];
            for (int e = lo + tid; e < hi; e += MAIN_BLOCK) {
                int2 r = recs[e];
                unsigned pk = (unsigned)r.x;
                float l0 = __int_as_float(r.y);
                float2 P0 = tileA[pk & 0x3fff];
                float2 P1 = t1[pk >> 14];
                float dx = P0.x - P1.x;
                float dy = P0.y - P1.y;
                float d = sqrtf(dx * dx + dy * dy) - l0;
                acc += d * d;
            }
            if (b + 1 < T_TILES) {
                __syncthreads();       // all readers of tileB (tile b) done
                {                      // commit tile b+1 from regs
                    float4* d = (float4*)tileB;
                    #pragma unroll
                    for (int k = 0; k < CHUNKS; ++k) {
                        int idx = tid + k * MAIN_BLOCK;
                        if (idx < TILE_F4) d[idx] = rB[k];
                    }
                }
                if (b + 2 < T_TILES) { // prefetch tile b+2 -> regs
                    const float4* g = (const float4*)(pb + (b + 2) * PTILE);
                    #pragma unroll
                    for (int k = 0; k < CHUNKS; ++k) {
                        int idx = tid + k * MAIN_BLOCK;
                        if (idx < TILE_F4) rB[k] = g[idx];
                    }
                }
                __syncthreads();       // tile b+1 visible
            }
        }

        if (tid == 0) sh_w = atomicAdd(&rowctr[slot], 1);
        __syncthreads();               // sh_w visible; all compute done
        w = sh_w;
    }

    // block reduction
    #pragma unroll
    for (int offx = 32; offx > 0; offx >>= 1)
        acc += __shfl_down(acc, offx, 64);
    int lane = tid & 63;
    int wave = tid >> 6;
    if (lane == 0) wsum[wave] = acc;
    __syncthreads();
    if (wave == 0) {
        float v = (lane < MAIN_BLOCK / 64) ? wsum[lane] : 0.0f;
        #pragma unroll
        for (int offx = 8; offx > 0; offx >>= 1)
            v += __shfl_down(v, offx, 64);
        if (lane == 0) atomicAdd(out, v * inv_E);
    }
}

// ---------- fallback (R2 style) ----------
__global__ __launch_bounds__(256) void skeleton_loss_fallback(
    const float2* __restrict__ pts, const int* __restrict__ skel,
    const float* __restrict__ init_len, float* __restrict__ out,
    int N, int E, float inv_E)
{
    const int L = blockIdx.x;
    const int slot = L & 7;
    const int j = L >> 3;
    int e = j * 256 + threadIdx.x;
    float acc = 0.0f;
    if (e < E) {
        int i0 = skel[2 * e], i1 = skel[2 * e + 1];
        float l0 = init_len[e];
        for (int bb = 0; bb < 8; ++bb) {
            const float2* p = pts + (size_t)(slot * 8 + bb) * N;
            float2 s = p[i0], d = p[i1];
            float dx = s.x - d.x, dy = s.y - d.y;
            float len = sqrtf(dx * dx + dy * dy);
            float df = len - l0;
            acc += df * df;
        }
    }
    #pragma unroll
    for (int offx = 32; offx > 0; offx >>= 1)
        acc += __shfl_down(acc, offx, 64);
    __shared__ float ws[4];
    if ((threadIdx.x & 63) == 0) ws[threadIdx.x >> 6] = acc;
    __syncthreads();
    if (threadIdx.x == 0)
        atomicAdd(out, (ws[0] + ws[1] + ws[2] + ws[3]) * inv_E);
}

extern "C" void kernel_launch(void* const* d_in, const int* in_sizes, int n_in,
                              void* d_out, int out_size, void* d_ws, size_t ws_size,
                              hipStream_t stream) {
    const float2* pts      = (const float2*)d_in[0];
    const int*    skel     = (const int*)d_in[1];
    const float*  init_len = (const float*)d_in[2];
    float*        out      = (float*)d_out;

    const int B = 64;
    const int E = in_sizes[2];
    const int N = in_sizes[0] / (B * 2);
    const float inv_E = 1.0f / (float)E;

    hipMemsetAsync(out, 0, sizeof(float), stream);

    const size_t ws_need = (size_t)WS_REC + (size_t)E * 8;
    const bool ok = (ws_size >= ws_need) && (N == T_TILES * PTILE);

    if (!ok) {
        dim3 grid(((E + 255) / 256) * 8);
        skeleton_loss_fallback<<<grid, 256, 0, stream>>>(
            pts, skel, init_len, out, N, E, inv_E);
        return;
    }

    char* ws = (char*)d_ws;
    int* cnt    = (int*)(ws + WS_CNT);
    int* off    = (int*)(ws + WS_OFF);
    int* cur    = (int*)(ws + WS_CUR);
    int* rowctr = (int*)(ws + WS_CTR);
    int2* recs  = (int2*)(ws + WS_REC);

    hipMemsetAsync(ws, 0, 4096, stream);   // cnt + rowctr (off/cur set by scan)

    int nblk = (E + 1023) / 1024;
    hist_kernel<<<nblk, 1024, 0, stream>>>((const int2*)skel, cnt, E);
    scan_kernel<<<1, 256, 0, stream>>>(cnt, off, cur);
    scatter_kernel<<<nblk, 1024, 0, stream>>>((const int2*)skel, init_len, cur, recs, E);
    skeleton_main_kernel<<<256, MAIN_BLOCK, 0, stream>>>(
        pts, recs, off, rowctr, out, N, inv_E);
}

// Round 5
// 131.624 us; speedup vs baseline: 1.7094x; 1.7094x over previous
//
#include <hip/hip_runtime.h>
#include <hip/hip_bf16.h>

// SkeletonLoss: out = sum_b mean_e ( ||p[b,s0]-p[b,s1]|| - init_len[e] )^2
// B=64, N=100000, E=200000.
//
// R5: row-sweep tile pairs, staged entirely with global_load_lds (async DMA,
// no VGPR round-trip -- R4's register double-buffer spilled to scratch, 430 MB
// of traffic). Points: 10 full tiles of 10000 (80 KB) / 20 half-tiles of 5000
// (40 KB). Edges bucketed by (full tile a = min, half tile bh of the other
// endpoint): 200 buckets, contiguous recs. Main kernel: 256 blocks (1/CU),
// LDS = tileA(80K) + bufB[2](40K each). Work item (batch, row a): pin tile a,
// sweep bh=2a..19; diag halves read from tileA. __syncthreads drains vmcnt(0),
// so: half-tile DMA issued AFTER barrier k overlaps bucket k's compute and is
// ready at barrier k+1; recs prefetch (named regs, no arrays) issued BEFORE
// the barrier has zero exposed latency. XCD-affine: block%8 = slot owns
// batches [slot*8, slot*8+8); per-slot dynamic row queue, heavy rows first.

#define T_TILES 10
#define PTILE   10000
#define HALF    5000
#define NB      200
#define MAIN_BLOCK 1024

// ---- ws layout (bytes) ----
#define WS_CNT  0      // cnt[256]
#define WS_OFF  1024   // off[257]
#define WS_CUR  2176   // cur[256]
#define WS_CTR  3200   // rowctr[8]
#define WS_REC  4096   // recs int2[E]

__device__ __forceinline__ void ld16(const float4* g, const float4* l) {
    __builtin_amdgcn_global_load_lds(
        (const __attribute__((address_space(1))) unsigned int*)g,
        (__attribute__((address_space(3))) unsigned int*)(unsigned)(uintptr_t)l,
        16, 0, 0);
}

// async stage nbytes (multiple of 16) from global -> LDS; tails are
// prefix-active in each wave (safe for wave-uniform-base LDS DMA).
__device__ __forceinline__ void stage_tile(const float2* g, float2* l,
                                           int nbytes, int tid) {
    const float4* gs = (const float4*)g;
    const float4* ls = (const float4*)l;
    int n = nbytes >> 4;
    for (int i = tid; i < n; i += MAIN_BLOCK) ld16(gs + i, ls + i);
}

__device__ __forceinline__ float eval_edge(int2 r, const float2* t0,
                                           const float2* t1) {
    unsigned pk = (unsigned)r.x;
    float l0 = __int_as_float(r.y);
    float2 P0 = t0[pk & 0x3fff];
    float2 P1 = t1[pk >> 14];
    float dx = P0.x - P1.x, dy = P0.y - P1.y;
    float d = sqrtf(dx * dx + dy * dy) - l0;
    return d * d;
}

__device__ __forceinline__ void pre3(const int2* __restrict__ recs, int lo,
                                     int hi, int tid, int2& r0, int2& r1,
                                     int2& r2) {
    int e = lo + tid;
    r0 = (e < hi) ? recs[e] : make_int2(0, 0);
    r1 = (e + 1024 < hi) ? recs[e + 1024] : make_int2(0, 0);
    r2 = (e + 2048 < hi) ? recs[e + 2048] : make_int2(0, 0);
}

__device__ __forceinline__ float bucket3(int2 r0, int2 r1, int2 r2, int lo,
                                         int hi, int tid, const float2* t0,
                                         const float2* t1,
                                         const int2* __restrict__ recs) {
    float acc = 0.0f;
    int n = hi - lo;
    if (tid < n) acc += eval_edge(r0, t0, t1);
    if (tid + 1024 < n) acc += eval_edge(r1, t0, t1);
    if (tid + 2048 < n) acc += eval_edge(r2, t0, t1);
    for (int e = lo + tid + 3072; e < hi; e += 1024)   // safety (never in practice)
        acc += eval_edge(recs[e], t0, t1);
    return acc;
}

__device__ __forceinline__ void edge_bucket(int i0, int i1, int& bkt,
                                            unsigned& pk) {
    int ta = i0 / PTILE, tb = i1 / PTILE;
    int A  = (tb < ta) ? i1 : i0;
    int Bp = (tb < ta) ? i0 : i1;
    int a  = (tb < ta) ? tb : ta;
    int bh = Bp / HALF;                  // 0..19
    int oA = A - a * PTILE;              // 14 bits
    int oB = Bp - bh * HALF;             // 13 bits
    bkt = a * 20 + bh;
    pk = (unsigned)oA | ((unsigned)oB << 14);
}

__global__ __launch_bounds__(1024) void hist_kernel(
    const int2* __restrict__ skel, int* __restrict__ cnt, int E)
{
    __shared__ int h[256];
    if (threadIdx.x < 256) h[threadIdx.x] = 0;
    __syncthreads();
    int e = blockIdx.x * blockDim.x + threadIdx.x;
    if (e < E) {
        int2 s = skel[e];
        int bkt; unsigned pk;
        edge_bucket(s.x, s.y, bkt, pk);
        atomicAdd(&h[bkt], 1);
    }
    __syncthreads();
    if (threadIdx.x < 256 && h[threadIdx.x])
        atomicAdd(&cnt[threadIdx.x], h[threadIdx.x]);
}

__global__ __launch_bounds__(256) void scan_kernel(
    const int* __restrict__ cnt, int* __restrict__ off, int* __restrict__ cur)
{
    __shared__ int s[256];
    int t = threadIdx.x;
    int v = cnt[t];
    s[t] = v;
    __syncthreads();
    #pragma unroll
    for (int d = 1; d < 256; d <<= 1) {
        int x = (t >= d) ? s[t - d] : 0;
        __syncthreads();
        s[t] += x;
        __syncthreads();
    }
    int ex = s[t] - v;
    if (t <= NB) off[t] = ex;
    if (t < NB)  cur[t] = ex;
}

__global__ __launch_bounds__(1024) void scatter_kernel(
    const int2* __restrict__ skel, const float* __restrict__ init_len,
    int* __restrict__ cur, int2* __restrict__ recs, int E)
{
    __shared__ int h[256];
    __shared__ int base[256];
    if (threadIdx.x < 256) h[threadIdx.x] = 0;
    __syncthreads();
    int e = blockIdx.x * blockDim.x + threadIdx.x;
    int bkt = 0, lrank = 0; unsigned pk = 0;
    if (e < E) {
        int2 s = skel[e];
        edge_bucket(s.x, s.y, bkt, pk);
        lrank = atomicAdd(&h[bkt], 1);
    }
    __syncthreads();
    if (threadIdx.x < 256 && h[threadIdx.x])
        base[threadIdx.x] = atomicAdd(&cur[threadIdx.x], h[threadIdx.x]);
    __syncthreads();
    if (e < E) {
        int pos = base[bkt] + lrank;
        recs[pos] = make_int2((int)pk, __float_as_int(init_len[e]));
    }
}

__global__ __launch_bounds__(MAIN_BLOCK) void skeleton_main_kernel(
    const float2* __restrict__ pts, const int2* __restrict__ recs,
    const int* __restrict__ off, int* __restrict__ rowctr,
    float* __restrict__ out, int N, float inv_E)
{
    __shared__ float2 tileA[PTILE];      // 80000 B
    __shared__ float2 bufB[2][HALF];     // 2 x 40000 B
    __shared__ float wsum[MAIN_BLOCK / 64];
    __shared__ int sh_w;

    const int slot = blockIdx.x & 7;     // XCD affinity
    const int tid = threadIdx.x;
    float acc = 0.0f;

    if (tid == 0) sh_w = atomicAdd(&rowctr[slot], 1);
    __syncthreads();
    int w = sh_w;

    while (w < 8 * T_TILES) {
        const int a = w >> 3;            // heavy rows (a=0) first
        const int batch = slot * 8 + (w & 7);
        const float2* pb = pts + (size_t)batch * N;
        const int nb = 20 - 2 * a;       // buckets this row (>= 2)
        const int pbase = 22 * a;        // bucket id of k=0 (ids contiguous)

        // async DMA: tileA + first external half (prev row's readers are done:
        // the sh_w barrier below row end precedes this)
        stage_tile(pb + a * PTILE, tileA, 80000, tid);
        if (nb > 2) stage_tile(pb + (2 * a + 2) * HALF, bufB[0], 40000, tid);

        // recs prefetch for k=0,1 (drained by the same barrier)
        int lo0 = off[pbase],     hi0 = off[pbase + 1];
        int lo1 = hi0,            hi1 = off[pbase + 2];
        int2 ca, cb, cc, na, nb2, nc;
        pre3(recs, lo0, hi0, tid, ca, cb, cc);
        pre3(recs, lo1, hi1, tid, na, nb2, nc);
        __syncthreads();                 // tileA, bufB[0], recs(k0,k1) ready

        if (nb > 3) stage_tile(pb + (2 * a + 3) * HALF, bufB[1], 40000, tid);

        // k=0, k=1: diagonal halves, both endpoints in tileA
        acc += bucket3(ca, cb, cc, lo0, hi0, tid, tileA, tileA, recs);
        if (nb > 2) {                    // prefetch recs k=2 during k=1 compute
            int l2 = off[pbase + 2], h2 = off[pbase + 3];
            pre3(recs, l2, h2, tid, ca, cb, cc);
        }
        acc += bucket3(na, nb2, nc, lo1, hi1, tid, tileA, tileA + HALF, recs);

        int curbuf = 0;
        int k = 2;
        while (k < nb) {
            // ---- bucket k uses c-regs ----
            {
                int lo = off[pbase + k], hi = off[pbase + k + 1];
                if (k + 1 < nb)          // recs k+1 -> n-regs, before barrier
                    pre3(recs, hi, off[pbase + k + 2], tid, na, nb2, nc);
                __syncthreads();         // publish bufB[curbuf] = half 2a+k
                if (k >= 3 && k + 1 < nb)
                    stage_tile(pb + (2 * a + k + 1) * HALF, bufB[curbuf ^ 1],
                               40000, tid);
                acc += bucket3(ca, cb, cc, lo, hi, tid, tileA, bufB[curbuf], recs);
                curbuf ^= 1; ++k;
            }
            if (k >= nb) break;
            // ---- bucket k uses n-regs ----
            {
                int lo = off[pbase + k], hi = off[pbase + k + 1];
                if (k + 1 < nb)
                    pre3(recs, hi, off[pbase + k + 2], tid, ca, cb, cc);
                __syncthreads();
                if (k + 1 < nb)          // k >= 3 here always
                    stage_tile(pb + (2 * a + k + 1) * HALF, bufB[curbuf ^ 1],
                               40000, tid);
                acc += bucket3(na, nb2, nc, lo, hi, tid, tileA, bufB[curbuf], recs);
                curbuf ^= 1; ++k;
            }
        }

        if (tid == 0) sh_w = atomicAdd(&rowctr[slot], 1);
        __syncthreads();                 // all compute done; sh_w visible
        w = sh_w;
    }

    // block reduction
    #pragma unroll
    for (int offx = 32; offx > 0; offx >>= 1)
        acc += __shfl_down(acc, offx, 64);
    int lane = tid & 63;
    int wave = tid >> 6;
    if (lane == 0) wsum[wave] = acc;
    __syncthreads();
    if (wave == 0) {
        float v = (lane < MAIN_BLOCK / 64) ? wsum[lane] : 0.0f;
        #pragma unroll
        for (int offx = 8; offx > 0; offx >>= 1)
            v += __shfl_down(v, offx, 64);
        if (lane == 0) atomicAdd(out, v * inv_E);
    }
}

// ---------- fallback (R2 style) ----------
__global__ __launch_bounds__(256) void skeleton_loss_fallback(
    const float2* __restrict__ pts, const int* __restrict__ skel,
    const float* __restrict__ init_len, float* __restrict__ out,
    int N, int E, float inv_E)
{
    const int L = blockIdx.x;
    const int slot = L & 7;
    const int j = L >> 3;
    int e = j * 256 + threadIdx.x;
    float acc = 0.0f;
    if (e < E) {
        int i0 = skel[2 * e], i1 = skel[2 * e + 1];
        float l0 = init_len[e];
        for (int bb = 0; bb < 8; ++bb) {
            const float2* p = pts + (size_t)(slot * 8 + bb) * N;
            float2 s = p[i0], d = p[i1];
            float dx = s.x - d.x, dy = s.y - d.y;
            float df = sqrtf(dx * dx + dy * dy) - l0;
            acc += df * df;
        }
    }
    #pragma unroll
    for (int offx = 32; offx > 0; offx >>= 1)
        acc += __shfl_down(acc, offx, 64);
    __shared__ float ws[4];
    if ((threadIdx.x & 63) == 0) ws[threadIdx.x >> 6] = acc;
    __syncthreads();
    if (threadIdx.x == 0)
        atomicAdd(out, (ws[0] + ws[1] + ws[2] + ws[3]) * inv_E);
}

extern "C" void kernel_launch(void* const* d_in, const int* in_sizes, int n_in,
                              void* d_out, int out_size, void* d_ws, size_t ws_size,
                              hipStream_t stream) {
    const float2* pts      = (const float2*)d_in[0];
    const int*    skel     = (const int*)d_in[1];
    const float*  init_len = (const float*)d_in[2];
    float*        out      = (float*)d_out;

    const int B = 64;
    const int E = in_sizes[2];
    const int N = in_sizes[0] / (B * 2);
    const float inv_E = 1.0f / (float)E;

    hipMemsetAsync(out, 0, sizeof(float), stream);

    const size_t ws_need = (size_t)WS_REC + (size_t)E * 8;
    const bool ok = (ws_size >= ws_need) && (N == T_TILES * PTILE);

    if (!ok) {
        dim3 grid(((E + 255) / 256) * 8);
        skeleton_loss_fallback<<<grid, 256, 0, stream>>>(
            pts, skel, init_len, out, N, E, inv_E);
        return;
    }

    char* ws = (char*)d_ws;
    int* cnt    = (int*)(ws + WS_CNT);
    int* off    = (int*)(ws + WS_OFF);
    int* cur    = (int*)(ws + WS_CUR);
    int* rowctr = (int*)(ws + WS_CTR);
    int2* recs  = (int2*)(ws + WS_REC);

    hipMemsetAsync(ws, 0, 4096, stream);   // cnt + rowctr

    int nblk = (E + 1023) / 1024;
    hist_kernel<<<nblk, 1024, 0, stream>>>((const int2*)skel, cnt, E);
    scan_kernel<<<1, 256, 0, stream>>>(cnt, off, cur);
    scatter_kernel<<<nblk, 1024, 0, stream>>>((const int2*)skel, init_len, cur, recs, E);
    skeleton_main_kernel<<<256, MAIN_BLOCK, 0, stream>>>(
        pts, recs, off, rowctr, out, N, inv_E);
}